// Round 1
// baseline (39179.010 us; speedup 1.0000x reference)
//
#include <hip/hip_runtime.h>
#include <hip/hip_bf16.h>
#include <math.h>

#define T_STEPS 512
#define BATCH   64
#define IN_DIM  1024
#define HID     1024
#define G4      (4 * HID)            // 4096
#define MTOT    (T_STEPS * BATCH)    // 32768
#define TBH     ((size_t)T_STEPS * BATCH * HID)

// ---------------------------------------------------------------------------
// Phase 1: xg[m][n] = sum_k input[m][k] * Wih[n][k] + bih[n] + bhh[n]
// M=32768, N=4096, K=1024.  128x128 tile, BK=16, 256 threads, 8x8 microtile.
// ---------------------------------------------------------------------------
#define BM 128
#define BN 128
#define BK 16
#define LDT 132   // padded LDS leading dim (16B-aligned rows, bank-spread)

__global__ __launch_bounds__(256) void xgemm_kernel(
    const float* __restrict__ A, const float* __restrict__ W,
    const float* __restrict__ bih, const float* __restrict__ bhh,
    float* __restrict__ C) {
  __shared__ float As[BK][LDT];
  __shared__ float Ws[BK][LDT];
  const int tid = threadIdx.x;
  const int m0 = blockIdx.y * BM;
  const int n0 = blockIdx.x * BN;
  const int tx = tid & 15, ty = tid >> 4;
  const int srow = tid >> 2;          // 0..63
  const int scol = (tid & 3) << 2;    // 0,4,8,12

  float acc[8][8];
#pragma unroll
  for (int i = 0; i < 8; ++i)
#pragma unroll
    for (int j = 0; j < 8; ++j) acc[i][j] = 0.f;

  const float* Ap0 = A + (size_t)(m0 + srow) * IN_DIM + scol;
  const float* Ap1 = Ap0 + (size_t)64 * IN_DIM;
  const float* Wp0 = W + (size_t)(n0 + srow) * IN_DIM + scol;
  const float* Wp1 = Wp0 + (size_t)64 * IN_DIM;

  for (int k0 = 0; k0 < IN_DIM; k0 += BK) {
    float4 av0 = *(const float4*)(Ap0 + k0);
    float4 av1 = *(const float4*)(Ap1 + k0);
    float4 wv0 = *(const float4*)(Wp0 + k0);
    float4 wv1 = *(const float4*)(Wp1 + k0);
    As[scol + 0][srow]      = av0.x; As[scol + 1][srow]      = av0.y;
    As[scol + 2][srow]      = av0.z; As[scol + 3][srow]      = av0.w;
    As[scol + 0][srow + 64] = av1.x; As[scol + 1][srow + 64] = av1.y;
    As[scol + 2][srow + 64] = av1.z; As[scol + 3][srow + 64] = av1.w;
    Ws[scol + 0][srow]      = wv0.x; Ws[scol + 1][srow]      = wv0.y;
    Ws[scol + 2][srow]      = wv0.z; Ws[scol + 3][srow]      = wv0.w;
    Ws[scol + 0][srow + 64] = wv1.x; Ws[scol + 1][srow + 64] = wv1.y;
    Ws[scol + 2][srow + 64] = wv1.z; Ws[scol + 3][srow + 64] = wv1.w;
    __syncthreads();
#pragma unroll
    for (int k = 0; k < BK; ++k) {
      float4 a0 = *(const float4*)&As[k][ty * 8];
      float4 a1 = *(const float4*)&As[k][ty * 8 + 4];
      float4 w0 = *(const float4*)&Ws[k][tx * 8];
      float4 w1 = *(const float4*)&Ws[k][tx * 8 + 4];
      float a8[8] = {a0.x, a0.y, a0.z, a0.w, a1.x, a1.y, a1.z, a1.w};
      float w8[8] = {w0.x, w0.y, w0.z, w0.w, w1.x, w1.y, w1.z, w1.w};
#pragma unroll
      for (int i = 0; i < 8; ++i)
#pragma unroll
        for (int j = 0; j < 8; ++j)
          acc[i][j] = fmaf(a8[i], w8[j], acc[i][j]);
    }
    __syncthreads();
  }

  float bj[8];
#pragma unroll
  for (int j = 0; j < 8; ++j)
    bj[j] = bih[n0 + tx * 8 + j] + bhh[n0 + tx * 8 + j];
#pragma unroll
  for (int i = 0; i < 8; ++i) {
    float* cp = C + (size_t)(m0 + ty * 8 + i) * G4 + n0 + tx * 8;
    float4 s0 = make_float4(acc[i][0] + bj[0], acc[i][1] + bj[1],
                            acc[i][2] + bj[2], acc[i][3] + bj[3]);
    float4 s1 = make_float4(acc[i][4] + bj[4], acc[i][5] + bj[5],
                            acc[i][6] + bj[6], acc[i][7] + bj[7]);
    *(float4*)cp = s0;
    *(float4*)(cp + 4) = s1;
  }
}

// ---------------------------------------------------------------------------
// Phase 2: persistent recurrent kernel, 256 blocks x 512 threads (1 block/CU).
// Block owns 16 batches x 16 hidden cols (all 4 gates). W_hh slice (64 rows x
// 1024 k) lives in registers: thread (rg,kc) holds rows {4rg..4rg+3} x k-chunk
// [32kc,32kc+32).  Per-step device barrier: two-level atomic tree, one fresh
// counter set per step (re-zeroed by hipMemsetAsync each launch).
// ---------------------------------------------------------------------------
#define NBLK 256
#define BAR_STRIDE 320   // uints per step: 16 leaves * 16 spread + root + flag

__device__ __forceinline__ float sigm(float x) {
  return 1.f / (1.f + __expf(-x));
}
__device__ __forceinline__ float tanh_(float x) {
  return 2.f / (1.f + __expf(-2.f * x)) - 1.f;
}

__device__ __forceinline__ void gridbar(unsigned int* base) {
  __syncthreads();
  if (threadIdx.x == 0) {
    __threadfence();
    unsigned int* leaf = base + (blockIdx.x & 15) * 16;
    unsigned int lv = __hip_atomic_fetch_add(leaf, 1u, __ATOMIC_ACQ_REL,
                                             __HIP_MEMORY_SCOPE_AGENT);
    if (lv == (NBLK / 16) - 1) {
      unsigned int rv = __hip_atomic_fetch_add(base + 256, 1u, __ATOMIC_ACQ_REL,
                                               __HIP_MEMORY_SCOPE_AGENT);
      if (rv == 15u)
        __hip_atomic_store(base + 257, 1u, __ATOMIC_RELEASE,
                           __HIP_MEMORY_SCOPE_AGENT);
    }
    while (!__hip_atomic_load(base + 257, __ATOMIC_ACQUIRE,
                              __HIP_MEMORY_SCOPE_AGENT)) {
      __builtin_amdgcn_s_sleep(2);
    }
  }
  __syncthreads();
}

__global__ __launch_bounds__(512, 2) void recur_kernel(
    const float* __restrict__ xg,   // [T][B][4H]
    const float* __restrict__ Whh,  // [4H][H]
    const float* __restrict__ h0, const float* __restrict__ c0,
    const float* __restrict__ ret,  // [H]
    float* __restrict__ out,        // [T*B*H] outputs, then hT, then cT
    unsigned int* __restrict__ bar) {
  const int tid = threadIdx.x;
  const int cg = blockIdx.x & 63;   // hidden-col group
  const int bg = blockIdx.x >> 6;   // batch group
  const int b0 = bg * 16;
  const int colbase = cg * 16;

  const int rg = tid & 15;          // row group: rows 4rg..4rg+3 (local)
  const int kc = tid >> 4;          // 0..31, k-chunk [32kc, 32kc+32)
  const int kbase = kc * 32;
  const int wv = tid >> 6;          // wave id 0..7
  const int lane = tid & 63;

  // ---- load W_hh slice into registers: 4 rows x 32 k = 32 float4 ----
  float4 w4[4][8];
#pragma unroll
  for (int r = 0; r < 4; ++r) {
    int row_loc = rg * 4 + r;                       // 0..63
    int rowg = (row_loc >> 4) * HID + colbase + (row_loc & 15);  // gate row
    const float4* wp = (const float4*)(Whh + (size_t)rowg * HID + kbase);
#pragma unroll
    for (int kk = 0; kk < 8; ++kk) w4[r][kk] = wp[kk];
  }

  __shared__ float part[8][64][20];  // [wave][row_loc][batch], padded

  // ---- per-thread recurrent state (threads 0..255 do the update) ----
  const int uj = tid & 15;      // col offset
  const int ub = tid >> 4;      // batch offset (valid for tid<256)
  float c_reg = 0.f, h_reg = 0.f, r_coef = 0.f;
  if (tid < 256) {
    int gb = b0 + ub, gc = colbase + uj;
    c_reg = c0[gb * HID + gc];
    h_reg = h0[gb * HID + gc];
    r_coef = ret[gc];
  }

  for (int t = 0; t < T_STEPS; ++t) {
    const float* hsrc =
        (t == 0) ? h0 : (out + (size_t)(t - 1) * BATCH * HID);
    const float* hb = hsrc + (size_t)b0 * HID + kbase;

    // ---- register-tiled partial GEMM: acc[r][b] over this k-chunk ----
    float acc[4][16];
#pragma unroll
    for (int r = 0; r < 4; ++r)
#pragma unroll
      for (int b = 0; b < 16; ++b) acc[r][b] = 0.f;

#pragma unroll
    for (int kk = 0; kk < 8; ++kk) {
#pragma unroll
      for (int b = 0; b < 16; ++b) {
        float4 hv = *(const float4*)(hb + b * HID + kk * 4);
#pragma unroll
        for (int r = 0; r < 4; ++r) {
          acc[r][b] = fmaf(hv.x, w4[r][kk].x, acc[r][b]);
          acc[r][b] = fmaf(hv.y, w4[r][kk].y, acc[r][b]);
          acc[r][b] = fmaf(hv.z, w4[r][kk].z, acc[r][b]);
          acc[r][b] = fmaf(hv.w, w4[r][kk].w, acc[r][b]);
        }
      }
    }

    // ---- reduce the 4 k-chunks within each wave (lanes l, l^16, l^32) ----
#pragma unroll
    for (int r = 0; r < 4; ++r)
#pragma unroll
      for (int b = 0; b < 16; ++b) {
        float v = acc[r][b];
        v += __shfl_xor(v, 16, 64);
        v += __shfl_xor(v, 32, 64);
        acc[r][b] = v;
      }
    if (lane < 16) {  // lane == rg for these lanes
#pragma unroll
      for (int r = 0; r < 4; ++r) {
        int row_loc = lane * 4 + r;
#pragma unroll
        for (int b = 0; b < 16; ++b) part[wv][row_loc][b] = acc[r][b];
      }
    }
    __syncthreads();

    // ---- cross-wave reduce + gates + state update (threads 0..255) ----
    if (tid < 256) {
      float g[4];
#pragma unroll
      for (int q = 0; q < 4; ++q) {
        int row_loc = q * 16 + uj;
        float s = 0.f;
#pragma unroll
        for (int w = 0; w < 8; ++w) s += part[w][row_loc][ub];
        s += xg[((size_t)t * BATCH + b0 + ub) * G4 + q * HID + colbase + uj];
        g[q] = s;
      }
      float ig = sigm(g[0]);
      float fg = sigm(g[1]);
      float gg = tanh_(g[2]);
      float og = sigm(g[3]);
      float cy = fg * c_reg + ig * gg;
      float hy = og * tanh_(cy);
      hy = r_coef * h_reg + (1.f - r_coef) * hy;
      c_reg = cy;
      h_reg = hy;
      size_t oidx = ((size_t)t * BATCH + b0 + ub) * HID + colbase + uj;
      out[oidx] = hy;
      if (t == T_STEPS - 1) {
        out[TBH + (size_t)(b0 + ub) * HID + colbase + uj] = hy;
        out[TBH + (size_t)BATCH * HID + (size_t)(b0 + ub) * HID + colbase + uj] = cy;
      }
    }
    __syncthreads();  // protect LDS `part` before next step overwrites

    if (t + 1 < T_STEPS) gridbar(bar + (size_t)t * BAR_STRIDE);
  }
}

// ---------------------------------------------------------------------------
extern "C" void kernel_launch(void* const* d_in, const int* in_sizes, int n_in,
                              void* d_out, int out_size, void* d_ws,
                              size_t ws_size, hipStream_t stream) {
  const float* input = (const float*)d_in[0];
  const float* h0    = (const float*)d_in[1];
  const float* c0    = (const float*)d_in[2];
  const float* wih   = (const float*)d_in[3];
  const float* whh   = (const float*)d_in[4];
  const float* bih   = (const float*)d_in[5];
  const float* bhh   = (const float*)d_in[6];
  const float* ret   = (const float*)d_in[7];
  float* out = (float*)d_out;

  unsigned int* bar = (unsigned int*)d_ws;                 // 512*320*4 = 640 KB
  float* xg = (float*)((char*)d_ws + (1 << 20));           // [T][B][4H] f32

  // zero the per-step barrier counters (ws is re-poisoned before each launch)
  hipMemsetAsync(d_ws, 0, (size_t)T_STEPS * BAR_STRIDE * 4, stream);

  dim3 g1(G4 / BN, MTOT / BM);  // (32, 256)
  xgemm_kernel<<<g1, 256, 0, stream>>>(input, wih, bih, bhh, xg);
  recur_kernel<<<NBLK, 512, 0, stream>>>(xg, whh, h0, c0, ret, out, bar);
}

// Round 2
// 36303.311 us; speedup vs baseline: 1.0792x; 1.0792x over previous
//
#include <hip/hip_runtime.h>
#include <hip/hip_bf16.h>
#include <math.h>

#define T_STEPS 512
#define BATCH   64
#define IN_DIM  1024
#define HID     1024
#define G4      (4 * HID)            // 4096
#define MTOT    (T_STEPS * BATCH)    // 32768
#define TBH     ((size_t)T_STEPS * BATCH * HID)

// ---------------------------------------------------------------------------
// Phase 1: xg[m][n] = sum_k input[m][k] * Wih[n][k] + bih[n] + bhh[n]
// M=32768, N=4096, K=1024.  128x128 tile, BK=16, 256 threads, 8x8 microtile.
// ---------------------------------------------------------------------------
#define BM 128
#define BN 128
#define BK 16
#define LDT 132

__global__ __launch_bounds__(256) void xgemm_kernel(
    const float* __restrict__ A, const float* __restrict__ W,
    const float* __restrict__ bih, const float* __restrict__ bhh,
    float* __restrict__ C) {
  __shared__ float As[BK][LDT];
  __shared__ float Ws[BK][LDT];
  const int tid = threadIdx.x;
  const int m0 = blockIdx.y * BM;
  const int n0 = blockIdx.x * BN;
  const int tx = tid & 15, ty = tid >> 4;
  const int srow = tid >> 2;          // 0..63
  const int scol = (tid & 3) << 2;    // 0,4,8,12

  float acc[8][8];
#pragma unroll
  for (int i = 0; i < 8; ++i)
#pragma unroll
    for (int j = 0; j < 8; ++j) acc[i][j] = 0.f;

  const float* Ap0 = A + (size_t)(m0 + srow) * IN_DIM + scol;
  const float* Ap1 = Ap0 + (size_t)64 * IN_DIM;
  const float* Wp0 = W + (size_t)(n0 + srow) * IN_DIM + scol;
  const float* Wp1 = Wp0 + (size_t)64 * IN_DIM;

  for (int k0 = 0; k0 < IN_DIM; k0 += BK) {
    float4 av0 = *(const float4*)(Ap0 + k0);
    float4 av1 = *(const float4*)(Ap1 + k0);
    float4 wv0 = *(const float4*)(Wp0 + k0);
    float4 wv1 = *(const float4*)(Wp1 + k0);
    As[scol + 0][srow]      = av0.x; As[scol + 1][srow]      = av0.y;
    As[scol + 2][srow]      = av0.z; As[scol + 3][srow]      = av0.w;
    As[scol + 0][srow + 64] = av1.x; As[scol + 1][srow + 64] = av1.y;
    As[scol + 2][srow + 64] = av1.z; As[scol + 3][srow + 64] = av1.w;
    Ws[scol + 0][srow]      = wv0.x; Ws[scol + 1][srow]      = wv0.y;
    Ws[scol + 2][srow]      = wv0.z; Ws[scol + 3][srow]      = wv0.w;
    Ws[scol + 0][srow + 64] = wv1.x; Ws[scol + 1][srow + 64] = wv1.y;
    Ws[scol + 2][srow + 64] = wv1.z; Ws[scol + 3][srow + 64] = wv1.w;
    __syncthreads();
#pragma unroll
    for (int k = 0; k < BK; ++k) {
      float4 a0 = *(const float4*)&As[k][ty * 8];
      float4 a1 = *(const float4*)&As[k][ty * 8 + 4];
      float4 w0 = *(const float4*)&Ws[k][tx * 8];
      float4 w1 = *(const float4*)&Ws[k][tx * 8 + 4];
      float a8[8] = {a0.x, a0.y, a0.z, a0.w, a1.x, a1.y, a1.z, a1.w};
      float w8[8] = {w0.x, w0.y, w0.z, w0.w, w1.x, w1.y, w1.z, w1.w};
#pragma unroll
      for (int i = 0; i < 8; ++i)
#pragma unroll
        for (int j = 0; j < 8; ++j)
          acc[i][j] = fmaf(a8[i], w8[j], acc[i][j]);
    }
    __syncthreads();
  }

  float bj[8];
#pragma unroll
  for (int j = 0; j < 8; ++j)
    bj[j] = bih[n0 + tx * 8 + j] + bhh[n0 + tx * 8 + j];
#pragma unroll
  for (int i = 0; i < 8; ++i) {
    float* cp = C + (size_t)(m0 + ty * 8 + i) * G4 + n0 + tx * 8;
    float4 s0 = make_float4(acc[i][0] + bj[0], acc[i][1] + bj[1],
                            acc[i][2] + bj[2], acc[i][3] + bj[3]);
    float4 s1 = make_float4(acc[i][4] + bj[4], acc[i][5] + bj[5],
                            acc[i][6] + bj[6], acc[i][7] + bj[7]);
    *(float4*)cp = s0;
    *(float4*)(cp + 4) = s1;
  }
}

// ---------------------------------------------------------------------------
// Phase 2: persistent recurrent kernel, 256 blocks x 512 threads (1 block/CU).
// Block owns 16 batches x 16 hidden cols (all 4 gates). W_hh slice (64 rows x
// 1024 k) lives in registers: 128 VGPR/thread of weights + 64 of acc -> needs
// ~230 VGPR, so we PIN 2 waves/EU (256-VGPR budget) to prevent the spill that
// cost 34 GB of scratch traffic in round 1.
// Barrier: two-level atomic tree, RELAXED ops + single release/acquire fences
// (round 1's ACQUIRE-per-spin-poll invalidated L1/L2 continuously).
// ---------------------------------------------------------------------------
#define NBLK 256
#define BAR_STRIDE 320

__device__ __forceinline__ float sigm(float x) {
  return 1.f / (1.f + __expf(-x));
}
__device__ __forceinline__ float tanh_(float x) {
  return 2.f / (1.f + __expf(-2.f * x)) - 1.f;
}

__device__ __forceinline__ void gridbar(unsigned int* base) {
  __syncthreads();
  if (threadIdx.x == 0) {
    __threadfence();  // release: drain + write back this block's out[] stores
    unsigned int* leaf = base + (blockIdx.x & 15) * 16;
    unsigned int lv = __hip_atomic_fetch_add(leaf, 1u, __ATOMIC_RELAXED,
                                             __HIP_MEMORY_SCOPE_AGENT);
    if (lv == (NBLK / 16) - 1) {
      unsigned int rv = __hip_atomic_fetch_add(base + 256, 1u, __ATOMIC_RELAXED,
                                               __HIP_MEMORY_SCOPE_AGENT);
      if (rv == 15u)
        __hip_atomic_store(base + 257, 1u, __ATOMIC_RELAXED,
                           __HIP_MEMORY_SCOPE_AGENT);
    }
    while (!__hip_atomic_load(base + 257, __ATOMIC_RELAXED,
                              __HIP_MEMORY_SCOPE_AGENT)) {
      __builtin_amdgcn_s_sleep(4);
    }
    __threadfence();  // acquire: one invalidation per step, not per poll
  }
  __syncthreads();
}

__global__ __launch_bounds__(512)
__attribute__((amdgpu_waves_per_eu(2, 2)))  // exactly 2 waves/EU -> 256 VGPR budget
void recur_kernel(
    const float* __restrict__ xg,   // [T][B][4H]
    const float* __restrict__ Whh,  // [4H][H]
    const float* __restrict__ h0, const float* __restrict__ c0,
    const float* __restrict__ ret,  // [H]
    float* __restrict__ out,        // [T*B*H] outputs, then hT, then cT
    unsigned int* __restrict__ bar) {
  const int tid = threadIdx.x;
  const int cg = blockIdx.x & 63;   // hidden-col group
  const int bg = blockIdx.x >> 6;   // batch group
  const int b0 = bg * 16;
  const int colbase = cg * 16;

  const int rg = tid & 15;          // row group: rows 4rg..4rg+3 (local)
  const int kc = tid >> 4;          // 0..31, k-chunk [32kc, 32kc+32)
  const int kbase = kc * 32;
  const int wv = tid >> 6;          // wave id 0..7
  const int lane = tid & 63;

  // ---- load W_hh slice into registers: 4 rows x 32 k = 32 float4 ----
  float4 w4[4][8];
#pragma unroll
  for (int r = 0; r < 4; ++r) {
    int row_loc = rg * 4 + r;                       // 0..63
    int rowg = (row_loc >> 4) * HID + colbase + (row_loc & 15);  // gate row
    const float4* wp = (const float4*)(Whh + (size_t)rowg * HID + kbase);
#pragma unroll
    for (int kk = 0; kk < 8; ++kk) w4[r][kk] = wp[kk];
  }

  __shared__ float part[8][64][17];  // [wave][row_loc][batch]; pad 17: writes
                                     // stride 68B = 2-way (free), reads
                                     // 17*uj mod 32 all-distinct (conflict-free)

  // ---- per-thread recurrent state (threads 0..255 do the update) ----
  const int uj = tid & 15;      // col offset
  const int ub = tid >> 4;      // batch offset (valid for tid<256)
  float c_reg = 0.f, h_reg = 0.f, r_coef = 0.f;
  if (tid < 256) {
    int gb = b0 + ub, gc = colbase + uj;
    c_reg = c0[gb * HID + gc];
    h_reg = h0[gb * HID + gc];
    r_coef = ret[gc];
  }

  for (int t = 0; t < T_STEPS; ++t) {
    const float* hsrc =
        (t == 0) ? h0 : (out + (size_t)(t - 1) * BATCH * HID);
    const float* hb = hsrc + (size_t)b0 * HID + kbase;

    // ---- register-tiled partial GEMM: acc[r][b] over this k-chunk ----
    float acc[4][16];
#pragma unroll
    for (int r = 0; r < 4; ++r)
#pragma unroll
      for (int b = 0; b < 16; ++b) acc[r][b] = 0.f;

#pragma unroll
    for (int kk = 0; kk < 8; ++kk) {
#pragma unroll
      for (int b = 0; b < 16; ++b) {
        float4 hv = *(const float4*)(hb + b * HID + kk * 4);
#pragma unroll
        for (int r = 0; r < 4; ++r) {
          acc[r][b] = fmaf(hv.x, w4[r][kk].x, acc[r][b]);
          acc[r][b] = fmaf(hv.y, w4[r][kk].y, acc[r][b]);
          acc[r][b] = fmaf(hv.z, w4[r][kk].z, acc[r][b]);
          acc[r][b] = fmaf(hv.w, w4[r][kk].w, acc[r][b]);
        }
      }
    }

    // ---- reduce the 4 k-chunks within each wave (lanes l, l^16, l^32) ----
#pragma unroll
    for (int r = 0; r < 4; ++r)
#pragma unroll
      for (int b = 0; b < 16; ++b) {
        float v = acc[r][b];
        v += __shfl_xor(v, 16, 64);
        v += __shfl_xor(v, 32, 64);
        acc[r][b] = v;
      }
    if (lane < 16) {  // lane == rg for these lanes
#pragma unroll
      for (int r = 0; r < 4; ++r) {
        int row_loc = lane * 4 + r;
#pragma unroll
        for (int b = 0; b < 16; ++b) part[wv][row_loc][b] = acc[r][b];
      }
    }
    __syncthreads();

    // ---- cross-wave reduce + gates + state update (threads 0..255) ----
    if (tid < 256) {
      float g[4];
#pragma unroll
      for (int q = 0; q < 4; ++q) {
        int row_loc = q * 16 + uj;
        float s = 0.f;
#pragma unroll
        for (int w = 0; w < 8; ++w) s += part[w][row_loc][ub];
        s += xg[((size_t)t * BATCH + b0 + ub) * G4 + q * HID + colbase + uj];
        g[q] = s;
      }
      float ig = sigm(g[0]);
      float fg = sigm(g[1]);
      float gg = tanh_(g[2]);
      float og = sigm(g[3]);
      float cy = fg * c_reg + ig * gg;
      float hy = og * tanh_(cy);
      hy = r_coef * h_reg + (1.f - r_coef) * hy;
      c_reg = cy;
      h_reg = hy;
      size_t oidx = ((size_t)t * BATCH + b0 + ub) * HID + colbase + uj;
      out[oidx] = hy;
      if (t == T_STEPS - 1) {
        out[TBH + (size_t)(b0 + ub) * HID + colbase + uj] = hy;
        out[TBH + (size_t)BATCH * HID + (size_t)(b0 + ub) * HID + colbase + uj] = cy;
      }
    }
    __syncthreads();  // protect LDS `part` before next step overwrites

    if (t + 1 < T_STEPS) gridbar(bar + (size_t)t * BAR_STRIDE);
  }
}

// ---------------------------------------------------------------------------
extern "C" void kernel_launch(void* const* d_in, const int* in_sizes, int n_in,
                              void* d_out, int out_size, void* d_ws,
                              size_t ws_size, hipStream_t stream) {
  const float* input = (const float*)d_in[0];
  const float* h0    = (const float*)d_in[1];
  const float* c0    = (const float*)d_in[2];
  const float* wih   = (const float*)d_in[3];
  const float* whh   = (const float*)d_in[4];
  const float* bih   = (const float*)d_in[5];
  const float* bhh   = (const float*)d_in[6];
  const float* ret   = (const float*)d_in[7];
  float* out = (float*)d_out;

  unsigned int* bar = (unsigned int*)d_ws;                 // 512*320*4 = 640 KB
  float* xg = (float*)((char*)d_ws + (1 << 20));           // [T][B][4H] f32

  hipMemsetAsync(d_ws, 0, (size_t)T_STEPS * BAR_STRIDE * 4, stream);

  dim3 g1(G4 / BN, MTOT / BM);  // (32, 256)
  xgemm_kernel<<<g1, 256, 0, stream>>>(input, wih, bih, bhh, xg);
  recur_kernel<<<NBLK, 512, 0, stream>>>(xg, whh, h0, c0, ret, out, bar);
}

// Round 3
// 23252.892 us; speedup vs baseline: 1.6849x; 1.5612x over previous
//
#include <hip/hip_runtime.h>
#include <hip/hip_bf16.h>
#include <math.h>

#define T_STEPS 512
#define BATCH   64
#define IN_DIM  1024
#define HID     1024
#define G4      (4 * HID)            // 4096
#define MTOT    (T_STEPS * BATCH)    // 32768
#define TBH     ((size_t)T_STEPS * BATCH * HID)

// ---------------------------------------------------------------------------
// Phase 1: xg[m][n] = sum_k input[m][k] * Wih[n][k] + bih[n] + bhh[n]
// (unchanged from round 2 — ~5 ms; optimize after recur is fixed)
// ---------------------------------------------------------------------------
#define BM 128
#define BN 128
#define BK 16
#define LDT 132

__global__ __launch_bounds__(256) void xgemm_kernel(
    const float* __restrict__ A, const float* __restrict__ W,
    const float* __restrict__ bih, const float* __restrict__ bhh,
    float* __restrict__ C) {
  __shared__ float As[BK][LDT];
  __shared__ float Ws[BK][LDT];
  const int tid = threadIdx.x;
  const int m0 = blockIdx.y * BM;
  const int n0 = blockIdx.x * BN;
  const int tx = tid & 15, ty = tid >> 4;
  const int srow = tid >> 2;          // 0..63
  const int scol = (tid & 3) << 2;    // 0,4,8,12

  float acc[8][8];
#pragma unroll
  for (int i = 0; i < 8; ++i)
#pragma unroll
    for (int j = 0; j < 8; ++j) acc[i][j] = 0.f;

  const float* Ap0 = A + (size_t)(m0 + srow) * IN_DIM + scol;
  const float* Ap1 = Ap0 + (size_t)64 * IN_DIM;
  const float* Wp0 = W + (size_t)(n0 + srow) * IN_DIM + scol;
  const float* Wp1 = Wp0 + (size_t)64 * IN_DIM;

  for (int k0 = 0; k0 < IN_DIM; k0 += BK) {
    float4 av0 = *(const float4*)(Ap0 + k0);
    float4 av1 = *(const float4*)(Ap1 + k0);
    float4 wv0 = *(const float4*)(Wp0 + k0);
    float4 wv1 = *(const float4*)(Wp1 + k0);
    As[scol + 0][srow]      = av0.x; As[scol + 1][srow]      = av0.y;
    As[scol + 2][srow]      = av0.z; As[scol + 3][srow]      = av0.w;
    As[scol + 0][srow + 64] = av1.x; As[scol + 1][srow + 64] = av1.y;
    As[scol + 2][srow + 64] = av1.z; As[scol + 3][srow + 64] = av1.w;
    Ws[scol + 0][srow]      = wv0.x; Ws[scol + 1][srow]      = wv0.y;
    Ws[scol + 2][srow]      = wv0.z; Ws[scol + 3][srow]      = wv0.w;
    Ws[scol + 0][srow + 64] = wv1.x; Ws[scol + 1][srow + 64] = wv1.y;
    Ws[scol + 2][srow + 64] = wv1.z; Ws[scol + 3][srow + 64] = wv1.w;
    __syncthreads();
#pragma unroll
    for (int k = 0; k < BK; ++k) {
      float4 a0 = *(const float4*)&As[k][ty * 8];
      float4 a1 = *(const float4*)&As[k][ty * 8 + 4];
      float4 w0 = *(const float4*)&Ws[k][tx * 8];
      float4 w1 = *(const float4*)&Ws[k][tx * 8 + 4];
      float a8[8] = {a0.x, a0.y, a0.z, a0.w, a1.x, a1.y, a1.z, a1.w};
      float w8[8] = {w0.x, w0.y, w0.z, w0.w, w1.x, w1.y, w1.z, w1.w};
#pragma unroll
      for (int i = 0; i < 8; ++i)
#pragma unroll
        for (int j = 0; j < 8; ++j)
          acc[i][j] = fmaf(a8[i], w8[j], acc[i][j]);
    }
    __syncthreads();
  }

  float bj[8];
#pragma unroll
  for (int j = 0; j < 8; ++j)
    bj[j] = bih[n0 + tx * 8 + j] + bhh[n0 + tx * 8 + j];
#pragma unroll
  for (int i = 0; i < 8; ++i) {
    float* cp = C + (size_t)(m0 + ty * 8 + i) * G4 + n0 + tx * 8;
    float4 s0 = make_float4(acc[i][0] + bj[0], acc[i][1] + bj[1],
                            acc[i][2] + bj[2], acc[i][3] + bj[3]);
    float4 s1 = make_float4(acc[i][4] + bj[4], acc[i][5] + bj[5],
                            acc[i][6] + bj[6], acc[i][7] + bj[7]);
    *(float4*)cp = s0;
    *(float4*)(cp + 4) = s1;
  }
}

// ---------------------------------------------------------------------------
// Phase 2: persistent recurrent kernel, 256 blocks x 512 threads (1 block/CU).
// Block owns 16 batches x 16 hidden cols x 4 gates = 64 gate-rows x K=1024.
// ROUND 3: weights are STREAMED from L2/LLC every step (16 MB unique chip-wide,
// ~0.5-2 us/step) instead of held in registers — rounds 1/2 proved the
// allocator refuses a >128-VGPR budget and spills 67 MB/step of scratch to
// HBM. The per-step k-chunk ROTATION (kct = (kc+t)&31) makes weight addresses
// t-dependent so the compiler CANNOT hoist the loads back into registers.
// ---------------------------------------------------------------------------
#define NBLK 256
#define BAR_STRIDE 320

__device__ __forceinline__ float sigm(float x) {
  return 1.f / (1.f + __expf(-x));
}
__device__ __forceinline__ float tanh_(float x) {
  return 2.f / (1.f + __expf(-2.f * x)) - 1.f;
}

__device__ __forceinline__ void gridbar(unsigned int* base) {
  __syncthreads();
  if (threadIdx.x == 0) {
    __threadfence();  // release: make this block's out[] stores visible
    unsigned int* leaf = base + (blockIdx.x & 15) * 16;
    unsigned int lv = __hip_atomic_fetch_add(leaf, 1u, __ATOMIC_RELAXED,
                                             __HIP_MEMORY_SCOPE_AGENT);
    if (lv == (NBLK / 16) - 1) {
      unsigned int rv = __hip_atomic_fetch_add(base + 256, 1u, __ATOMIC_RELAXED,
                                               __HIP_MEMORY_SCOPE_AGENT);
      if (rv == 15u)
        __hip_atomic_store(base + 257, 1u, __ATOMIC_RELAXED,
                           __HIP_MEMORY_SCOPE_AGENT);
    }
    while (!__hip_atomic_load(base + 257, __ATOMIC_RELAXED,
                              __HIP_MEMORY_SCOPE_AGENT)) {
      __builtin_amdgcn_s_sleep(2);
    }
    __threadfence();  // acquire: one invalidation per step, not per poll
  }
  __syncthreads();
}

__global__ __launch_bounds__(512) void recur_kernel(
    const float* __restrict__ xg,   // [T][B][4H]
    const float* __restrict__ Whh,  // [4H][H]
    const float* __restrict__ h0, const float* __restrict__ c0,
    const float* __restrict__ ret,  // [H]
    float* __restrict__ out,        // [T*B*H] outputs, then hT, then cT
    unsigned int* __restrict__ bar) {
  const int tid = threadIdx.x;
  const int cg = blockIdx.x & 63;   // hidden-col group
  const int bg = blockIdx.x >> 6;   // batch group
  const int b0 = bg * 16;
  const int colbase = cg * 16;

  const int rg = tid & 15;          // row group: local rows 4rg..4rg+3
  const int kc = tid >> 4;          // 0..31 (base k-chunk id, rotated per step)
  const int wv = tid >> 6;          // wave id 0..7
  const int lane = tid & 63;

  // per-thread weight row offsets (element offsets into Whh), loop-invariant
  size_t w_off[4];
#pragma unroll
  for (int r = 0; r < 4; ++r) {
    int row_loc = rg * 4 + r;                                    // 0..63
    int rowg = (row_loc >> 4) * HID + colbase + (row_loc & 15);  // gate*H + col
    w_off[r] = (size_t)rowg * HID;
  }

  __shared__ float part[8][64][17];

  // ---- per-thread recurrent state (threads 0..255 do the update) ----
  const int uj = tid & 15;      // col offset
  const int ub = tid >> 4;      // batch offset (valid for tid<256)
  float c_reg = 0.f, h_reg = 0.f, r_coef = 0.f;
  if (tid < 256) {
    int gb = b0 + ub, gc = colbase + uj;
    c_reg = c0[gb * HID + gc];
    h_reg = h0[gb * HID + gc];
    r_coef = ret[gc];
  }

  for (int t = 0; t < T_STEPS; ++t) {
    const float* hsrc =
        (t == 0) ? h0 : (out + (size_t)(t - 1) * BATCH * HID);
    const int kct = (kc + t) & 31;       // rotate chunks: defeats load hoisting
    const int kbase = kct * 32;
    const float* hb = hsrc + (size_t)b0 * HID + kbase;
    const float* wb = Whh + kbase;

    // issue-early: this step's xg values (consumed after the reduce)
    float xgv[4];
    if (tid < 256) {
      const float* xp =
          xg + ((size_t)t * BATCH + b0 + ub) * G4 + colbase + uj;
#pragma unroll
      for (int q = 0; q < 4; ++q) xgv[q] = xp[q * HID];
    }

    // ---- streamed-weight partial GEMM over this thread's k-chunk ----
    float acc[4][16];
#pragma unroll
    for (int r = 0; r < 4; ++r)
#pragma unroll
      for (int b = 0; b < 16; ++b) acc[r][b] = 0.f;

#pragma unroll
    for (int kk = 0; kk < 8; ++kk) {
      float4 wreg[4];
#pragma unroll
      for (int r = 0; r < 4; ++r)
        wreg[r] = *(const float4*)(wb + w_off[r] + kk * 4);
#pragma unroll
      for (int b = 0; b < 16; ++b) {
        float4 hv = *(const float4*)(hb + b * HID + kk * 4);
#pragma unroll
        for (int r = 0; r < 4; ++r) {
          acc[r][b] = fmaf(hv.x, wreg[r].x, acc[r][b]);
          acc[r][b] = fmaf(hv.y, wreg[r].y, acc[r][b]);
          acc[r][b] = fmaf(hv.z, wreg[r].z, acc[r][b]);
          acc[r][b] = fmaf(hv.w, wreg[r].w, acc[r][b]);
        }
      }
    }

    // ---- reduce the 4 k-chunks within each wave (lanes l, l^16, l^32) ----
#pragma unroll
    for (int r = 0; r < 4; ++r)
#pragma unroll
      for (int b = 0; b < 16; ++b) {
        float v = acc[r][b];
        v += __shfl_xor(v, 16, 64);
        v += __shfl_xor(v, 32, 64);
        acc[r][b] = v;
      }
    if (lane < 16) {  // lane == rg for these lanes
#pragma unroll
      for (int r = 0; r < 4; ++r) {
        int row_loc = lane * 4 + r;
#pragma unroll
        for (int b = 0; b < 16; ++b) part[wv][row_loc][b] = acc[r][b];
      }
    }
    __syncthreads();

    // ---- cross-wave reduce + gates + state update (threads 0..255) ----
    if (tid < 256) {
      float g[4];
#pragma unroll
      for (int q = 0; q < 4; ++q) {
        int row_loc = q * 16 + uj;
        float s = 0.f;
#pragma unroll
        for (int w = 0; w < 8; ++w) s += part[w][row_loc][ub];
        g[q] = s + xgv[q];
      }
      float ig = sigm(g[0]);
      float fg = sigm(g[1]);
      float gg = tanh_(g[2]);
      float og = sigm(g[3]);
      float cy = fg * c_reg + ig * gg;
      float hy = og * tanh_(cy);
      hy = r_coef * h_reg + (1.f - r_coef) * hy;
      c_reg = cy;
      h_reg = hy;
      size_t oidx = ((size_t)t * BATCH + b0 + ub) * HID + colbase + uj;
      out[oidx] = hy;
      if (t == T_STEPS - 1) {
        out[TBH + (size_t)(b0 + ub) * HID + colbase + uj] = hy;
        out[TBH + (size_t)BATCH * HID + (size_t)(b0 + ub) * HID + colbase + uj] = cy;
      }
    }
    __syncthreads();  // protect LDS `part` before next step overwrites

    if (t + 1 < T_STEPS) gridbar(bar + (size_t)t * BAR_STRIDE);
  }
}

// ---------------------------------------------------------------------------
extern "C" void kernel_launch(void* const* d_in, const int* in_sizes, int n_in,
                              void* d_out, int out_size, void* d_ws,
                              size_t ws_size, hipStream_t stream) {
  const float* input = (const float*)d_in[0];
  const float* h0    = (const float*)d_in[1];
  const float* c0    = (const float*)d_in[2];
  const float* wih   = (const float*)d_in[3];
  const float* whh   = (const float*)d_in[4];
  const float* bih   = (const float*)d_in[5];
  const float* bhh   = (const float*)d_in[6];
  const float* ret   = (const float*)d_in[7];
  float* out = (float*)d_out;

  unsigned int* bar = (unsigned int*)d_ws;                 // 512*320*4 = 640 KB
  float* xg = (float*)((char*)d_ws + (1 << 20));           // [T][B][4H] f32

  hipMemsetAsync(d_ws, 0, (size_t)T_STEPS * BAR_STRIDE * 4, stream);

  dim3 g1(G4 / BN, MTOT / BM);  // (32, 256)
  xgemm_kernel<<<g1, 256, 0, stream>>>(input, wih, bih, bhh, xg);
  recur_kernel<<<NBLK, 512, 0, stream>>>(xg, whh, h0, c0, ret, out, bar);
}

// Round 4
// 15779.071 us; speedup vs baseline: 2.4830x; 1.4737x over previous
//
#include <hip/hip_runtime.h>
#include <hip/hip_bf16.h>
#include <math.h>

#define T_STEPS 512
#define BATCH   64
#define IN_DIM  1024
#define HID     1024
#define G4      (4 * HID)            // 4096
#define MTOT    (T_STEPS * BATCH)    // 32768
#define TBH     ((size_t)T_STEPS * BATCH * HID)

// ---------------------------------------------------------------------------
// Phase 1: xg[m][n] = sum_k input[m][k] * Wih[n][k] + bih[n] + bhh[n]
// (unchanged — ~2.3 ms; optimize after recur is fixed)
// ---------------------------------------------------------------------------
#define BM 128
#define BN 128
#define BK 16
#define LDT 132

__global__ __launch_bounds__(256) void xgemm_kernel(
    const float* __restrict__ A, const float* __restrict__ W,
    const float* __restrict__ bih, const float* __restrict__ bhh,
    float* __restrict__ C) {
  __shared__ float As[BK][LDT];
  __shared__ float Ws[BK][LDT];
  const int tid = threadIdx.x;
  const int m0 = blockIdx.y * BM;
  const int n0 = blockIdx.x * BN;
  const int tx = tid & 15, ty = tid >> 4;
  const int srow = tid >> 2;          // 0..63
  const int scol = (tid & 3) << 2;    // 0,4,8,12

  float acc[8][8];
#pragma unroll
  for (int i = 0; i < 8; ++i)
#pragma unroll
    for (int j = 0; j < 8; ++j) acc[i][j] = 0.f;

  const float* Ap0 = A + (size_t)(m0 + srow) * IN_DIM + scol;
  const float* Ap1 = Ap0 + (size_t)64 * IN_DIM;
  const float* Wp0 = W + (size_t)(n0 + srow) * IN_DIM + scol;
  const float* Wp1 = Wp0 + (size_t)64 * IN_DIM;

  for (int k0 = 0; k0 < IN_DIM; k0 += BK) {
    float4 av0 = *(const float4*)(Ap0 + k0);
    float4 av1 = *(const float4*)(Ap1 + k0);
    float4 wv0 = *(const float4*)(Wp0 + k0);
    float4 wv1 = *(const float4*)(Wp1 + k0);
    As[scol + 0][srow]      = av0.x; As[scol + 1][srow]      = av0.y;
    As[scol + 2][srow]      = av0.z; As[scol + 3][srow]      = av0.w;
    As[scol + 0][srow + 64] = av1.x; As[scol + 1][srow + 64] = av1.y;
    As[scol + 2][srow + 64] = av1.z; As[scol + 3][srow + 64] = av1.w;
    Ws[scol + 0][srow]      = wv0.x; Ws[scol + 1][srow]      = wv0.y;
    Ws[scol + 2][srow]      = wv0.z; Ws[scol + 3][srow]      = wv0.w;
    Ws[scol + 0][srow + 64] = wv1.x; Ws[scol + 1][srow + 64] = wv1.y;
    Ws[scol + 2][srow + 64] = wv1.z; Ws[scol + 3][srow + 64] = wv1.w;
    __syncthreads();
#pragma unroll
    for (int k = 0; k < BK; ++k) {
      float4 a0 = *(const float4*)&As[k][ty * 8];
      float4 a1 = *(const float4*)&As[k][ty * 8 + 4];
      float4 w0 = *(const float4*)&Ws[k][tx * 8];
      float4 w1 = *(const float4*)&Ws[k][tx * 8 + 4];
      float a8[8] = {a0.x, a0.y, a0.z, a0.w, a1.x, a1.y, a1.z, a1.w};
      float w8[8] = {w0.x, w0.y, w0.z, w0.w, w1.x, w1.y, w1.z, w1.w};
#pragma unroll
      for (int i = 0; i < 8; ++i)
#pragma unroll
        for (int j = 0; j < 8; ++j)
          acc[i][j] = fmaf(a8[i], w8[j], acc[i][j]);
    }
    __syncthreads();
  }

  float bj[8];
#pragma unroll
  for (int j = 0; j < 8; ++j)
    bj[j] = bih[n0 + tx * 8 + j] + bhh[n0 + tx * 8 + j];
#pragma unroll
  for (int i = 0; i < 8; ++i) {
    float* cp = C + (size_t)(m0 + ty * 8 + i) * G4 + n0 + tx * 8;
    float4 s0 = make_float4(acc[i][0] + bj[0], acc[i][1] + bj[1],
                            acc[i][2] + bj[2], acc[i][3] + bj[3]);
    float4 s1 = make_float4(acc[i][4] + bj[4], acc[i][5] + bj[5],
                            acc[i][6] + bj[6], acc[i][7] + bj[7]);
    *(float4*)cp = s0;
    *(float4*)(cp + 4) = s1;
  }
}

// ---------------------------------------------------------------------------
// Phase 2 (ROUND 4): persistent kernel, 256 blocks x 512 thr, 1 block/CU.
// Block = 8 cols x 4 gates = 32 gate-rows x K=1024, 32 batches (half).
// W_hh slice lives in LDS (128 KB f32, loaded ONCE) -> immune to the per-step
// agent-acquire L2 invalidation that made round 3 latency-bound (24 MB/step
// re-fetch). LDS layout [k][32 rows], XOR-swizzled so a wave's 64 lanes
// (8 rg x 8 kc) read disjoint 16B bank slots. Wave = 4 batches x all K;
// butterfly reduce over kc within the wave; tiny 5 KB part buffer.
// Per-step k-chunk rotation defeats LDS-load hoisting (round-1/2 spill trap).
// ---------------------------------------------------------------------------
#define NBLK 256
#define BAR_STRIDE 320

__device__ __forceinline__ float sigm(float x) {
  return 1.f / (1.f + __expf(-x));
}
__device__ __forceinline__ float tanh_(float x) {
  return 2.f / (1.f + __expf(-2.f * x)) - 1.f;
}

__device__ __forceinline__ void gridbar(unsigned int* base) {
  __syncthreads();
  if (threadIdx.x == 0) {
    __threadfence();  // release
    unsigned int* leaf = base + (blockIdx.x & 15) * 16;
    unsigned int lv = __hip_atomic_fetch_add(leaf, 1u, __ATOMIC_RELAXED,
                                             __HIP_MEMORY_SCOPE_AGENT);
    if (lv == (NBLK / 16) - 1) {
      unsigned int rv = __hip_atomic_fetch_add(base + 256, 1u, __ATOMIC_RELAXED,
                                               __HIP_MEMORY_SCOPE_AGENT);
      if (rv == 15u)
        __hip_atomic_store(base + 257, 1u, __ATOMIC_RELAXED,
                           __HIP_MEMORY_SCOPE_AGENT);
    }
    while (!__hip_atomic_load(base + 257, __ATOMIC_RELAXED,
                              __HIP_MEMORY_SCOPE_AGENT)) {
      __builtin_amdgcn_s_sleep(2);
    }
    __threadfence();  // acquire (one L2 invalidation per step, not per poll)
  }
  __syncthreads();
}

__global__ __launch_bounds__(512) void recur_kernel(
    const float* __restrict__ xg,   // [T][B][4H]
    const float* __restrict__ Whh,  // [4H][H]
    const float* __restrict__ h0, const float* __restrict__ c0,
    const float* __restrict__ ret,  // [H]
    float* __restrict__ out,        // [T*B*H] outputs, then hT, then cT
    unsigned int* __restrict__ bar) {
  extern __shared__ float smem[];
  float* Wlds = smem;               // 32768 floats = 128 KB, [k][32 rows] swz
  float* part = smem + 32768;       // [8 waves][32 rows][5] = 5 KB

  const int tid = threadIdx.x;
  const int cg = blockIdx.x >> 1;   // 0..127 col-group (8 cols)
  const int bh = blockIdx.x & 1;    // batch half
  const int colbase = cg * 8;
  const int b0 = bh * 32;
  const int lane = tid & 63;
  const int wv = tid >> 6;          // wave 0..7 -> batches b0+4wv..+3
  const int rg = lane & 7;          // row group: rows 4rg..4rg+3
  const int kc = lane >> 3;         // base k-chunk 0..7 (128 k each)

  // ---- one-time: load W slice into LDS, layout [k][row], 16B-slot swizzle
  // byte(k,row) = k*128 + row*4, then slot bits 4..6 ^= (k ^ (k>>7)) & 7.
  {
    const int row_loc = tid >> 4;   // 0..31 (= gate*8 + col)
    const int kq = tid & 15;        // 64-k chunk
    const int g = row_loc >> 3, colz = row_loc & 7;
    const float* wrow =
        Whh + (size_t)(g * HID + colbase + colz) * HID + kq * 64;
    const int rowbyte = ((row_loc >> 2) << 4) + ((row_loc & 3) << 2);
#pragma unroll 4
    for (int k4 = 0; k4 < 64; k4 += 4) {
      float4 w4 = *(const float4*)(wrow + k4);
      float vals[4] = {w4.x, w4.y, w4.z, w4.w};
#pragma unroll
      for (int q = 0; q < 4; ++q) {
        int k = kq * 64 + k4 + q;
        int s = (k ^ (k >> 7)) & 7;
        *(float*)((char*)Wlds + (((k << 7) + rowbyte) ^ (s << 4))) = vals[q];
      }
    }
  }

  // ---- per-thread recurrent state (threads 0..255 do the update) ----
  const int ucol = tid & 7;         // col offset 0..7
  const int ubl = tid >> 3;         // batch offset 0..31 (valid for tid<256)
  float c_reg = 0.f, h_reg = 0.f, r_coef = 0.f;
  if (tid < 256) {
    int gb = b0 + ubl, gc = colbase + ucol;
    c_reg = c0[gb * HID + gc];
    h_reg = h0[gb * HID + gc];
    r_coef = ret[gc];
  }
  const int uw = ubl >> 2, ubb = ubl & 3;  // owning wave / batch-in-wave

  __syncthreads();  // Wlds ready

  for (int t = 0; t < T_STEPS; ++t) {
    const float* hsrc =
        (t == 0) ? h0 : (out + (size_t)(t - 1) * BATCH * HID);
    const int kct = (kc + t) & 7;           // rotate: defeats hoisting
    const int kcbase = kct * 128;
    const int kctx = kct << 4;              // swizzle contribution of k>>7
    const float* hb = hsrc + (size_t)(b0 + (wv << 2)) * HID + kcbase;

    // issue-early: this step's xg values
    float xgv[4];
    if (tid < 256) {
      const float* xp =
          xg + ((size_t)t * BATCH + b0 + ubl) * G4 + colbase + ucol;
#pragma unroll
      for (int q = 0; q < 4; ++q) xgv[q] = xp[q * HID];
    }

    // ---- GEMV over this thread's 128-k chunk: 4 rows x 4 batches ----
    float acc[4][4];
#pragma unroll
    for (int r = 0; r < 4; ++r)
#pragma unroll
      for (int b = 0; b < 4; ++b) acc[r][b] = 0.f;

    for (int kk = 0; kk < 128; kk += 4) {
      float ha[4][4];  // [batch][q]
      *(float4*)&ha[0][0] = *(const float4*)(hb + 0 * HID + kk);
      *(float4*)&ha[1][0] = *(const float4*)(hb + 1 * HID + kk);
      *(float4*)&ha[2][0] = *(const float4*)(hb + 2 * HID + kk);
      *(float4*)&ha[3][0] = *(const float4*)(hb + 3 * HID + kk);
#pragma unroll
      for (int q = 0; q < 4; ++q) {
        int k = kcbase + kk + q;
        int addr = (k << 7) + ((rg << 4) ^ ((((kk + q) & 7) << 4) ^ kctx));
        float wa[4];
        *(float4*)wa = *(const float4*)((const char*)Wlds + addr);
#pragma unroll
        for (int r = 0; r < 4; ++r)
#pragma unroll
          for (int b = 0; b < 4; ++b)
            acc[r][b] = fmaf(wa[r], ha[b][q], acc[r][b]);
      }
    }

    // ---- butterfly reduce over kc (lane bits 3,4,5) ----
#pragma unroll
    for (int r = 0; r < 4; ++r)
#pragma unroll
      for (int b = 0; b < 4; ++b) {
        float v = acc[r][b];
        v += __shfl_xor(v, 8, 64);
        v += __shfl_xor(v, 16, 64);
        v += __shfl_xor(v, 32, 64);
        acc[r][b] = v;
      }
    if (lane < 8) {  // lane == rg; write final sums for this wave's 4 batches
#pragma unroll
      for (int r = 0; r < 4; ++r) {
        int row = lane * 4 + r;
#pragma unroll
        for (int b = 0; b < 4; ++b) part[(wv * 32 + row) * 5 + b] = acc[r][b];
      }
    }
    __syncthreads();

    // ---- gates + state update (threads 0..255) ----
    if (tid < 256) {
      float g[4];
#pragma unroll
      for (int q = 0; q < 4; ++q)
        g[q] = part[(uw * 32 + q * 8 + ucol) * 5 + ubb] + xgv[q];
      float ig = sigm(g[0]);
      float fg = sigm(g[1]);
      float gg = tanh_(g[2]);
      float og = sigm(g[3]);
      float cy = fg * c_reg + ig * gg;
      float hy = og * tanh_(cy);
      hy = r_coef * h_reg + (1.f - r_coef) * hy;
      c_reg = cy;
      h_reg = hy;
      size_t oidx = ((size_t)t * BATCH + b0 + ubl) * HID + colbase + ucol;
      out[oidx] = hy;
      if (t == T_STEPS - 1) {
        size_t tb = TBH + (size_t)(b0 + ubl) * HID + colbase + ucol;
        out[tb] = hy;
        out[tb + (size_t)BATCH * HID] = cy;
      }
    }

    if (t + 1 < T_STEPS) {
      gridbar(bar + (size_t)t * BAR_STRIDE);  // starts with __syncthreads()
    }
  }
}

// ---------------------------------------------------------------------------
extern "C" void kernel_launch(void* const* d_in, const int* in_sizes, int n_in,
                              void* d_out, int out_size, void* d_ws,
                              size_t ws_size, hipStream_t stream) {
  const float* input = (const float*)d_in[0];
  const float* h0    = (const float*)d_in[1];
  const float* c0    = (const float*)d_in[2];
  const float* wih   = (const float*)d_in[3];
  const float* whh   = (const float*)d_in[4];
  const float* bih   = (const float*)d_in[5];
  const float* bhh   = (const float*)d_in[6];
  const float* ret   = (const float*)d_in[7];
  float* out = (float*)d_out;

  unsigned int* bar = (unsigned int*)d_ws;                 // 512*320*4 = 640 KB
  float* xg = (float*)((char*)d_ws + (1 << 20));           // [T][B][4H] f32

  hipMemsetAsync(d_ws, 0, (size_t)T_STEPS * BAR_STRIDE * 4, stream);

  dim3 g1(G4 / BN, MTOT / BM);  // (32, 256)
  xgemm_kernel<<<g1, 256, 0, stream>>>(input, wih, bih, bhh, xg);

  const size_t recur_lds = (32768 + 8 * 32 * 5) * sizeof(float);  // 136192 B
  recur_kernel<<<NBLK, 512, recur_lds, stream>>>(xg, whh, h0, c0, ret, out,
                                                 bar);
}